// Round 7
// baseline (42.153 us; speedup 1.0000x reference)
//
#include <hip/hip_runtime.h>

#define ALPHA 0.5f
#define NCLS 86
#define FEAT 256
#define NTOT 131072

constexpr int K    = 64;          // sample chunks
constexpr int CH   = NTOT / K;    // 2048 samples per chunk (one wave each)
constexpr int LCAP = 512;         // per-wave LDS index-list capacity

typedef float vf4 __attribute__((ext_vector_type(4)));   // native vec for nontemporal

// ws layout (floats):
//   S_part   [NCLS][K][FEAT]  = 1409024
//   cnt_part [NCLS][K]        = 5504
//   l2_part  [NCLS][K]        = 5504
//   class_loss [NCLS]         = 86
constexpr size_t WS_S   = 0;
constexpr size_t WS_CNT = (size_t)NCLS * K * FEAT;
constexpr size_t WS_L2  = WS_CNT + (size_t)NCLS * K;
constexpr size_t WS_CLS = WS_L2 + (size_t)NCLS * K;

// W-wide gather: issue W independent 16B/lane row-loads, then accumulate.
// Fully unrolled -> static indexing -> stays in registers (rule #20).
template<int W>
__device__ __forceinline__ void gatherW(const vf4* __restrict__ feat4,
                                        const int* wl, int i, int lane,
                                        vf4& acc, float& acc2)
{
    vf4 v[W];
#pragma unroll
    for (int j = 0; j < W; ++j)
        v[j] = __builtin_nontemporal_load(&feat4[(size_t)wl[i + j] * 64 + lane]);
#pragma unroll
    for (int j = 0; j < W; ++j) {
        acc += v[j];
        acc2 += v[j].x * v[j].x + v[j].y * v[j].y
              + v[j].z * v[j].z + v[j].w * v[j].w;
    }
}

// 128-thread blocks (2 waves), 2752 blocks. __launch_bounds__(128,6) caps
// VGPRs so 12 blocks/CU (24 waves/CU) co-reside -> one scheduling round.
__global__ __launch_bounds__(128, 6) void ctc_main(
    const vf4* __restrict__ feat4, const int4* __restrict__ lab4,
    vf4* __restrict__ S_part4, float* __restrict__ cnt_part,
    float* __restrict__ l2_part)
{
    __shared__ int list[2][LCAP];
    const int wave = threadIdx.x >> 6;
    const int lane = threadIdx.x & 63;
    const int pair = blockIdx.x * 2 + wave;   // = c*K + k
    const int k = pair % K;
    const int c = pair / K;
    const int base = k * CH;
    int* wl = list[wave];

    const int4* lp = lab4 + (base >> 2) + lane;
    const unsigned long long ltm = ((unsigned long long)1 << lane) - 1;

    vf4 acc = {0.f, 0.f, 0.f, 0.f};
    float acc2 = 0.f;
    int total = 0, nl = 0;

    auto drain = [&]() {
        int i = 0;
        for (; i + 4 <= nl; i += 4) gatherW<4>(feat4, wl, i, lane, acc, acc2);
        if (i + 2 <= nl) { gatherW<2>(feat4, wl, i, lane, acc, acc2); i += 2; }
        if (i < nl)        gatherW<1>(feat4, wl, i, lane, acc, acc2);
        nl = 0;
    };

    // scan phase: compact matching sample indices into the LDS list
    for (int h = 0; h < 2; ++h) {
        int4 Lr[4];
#pragma unroll
        for (int q = 0; q < 4; ++q) Lr[q] = lp[(h * 4 + q) * 64];
#pragma unroll
        for (int q = 0; q < 4; ++q) {
            const int4 Lc = Lr[q];
            const int sbase = base + ((h * 4 + q) * 64 + lane) * 4;
            unsigned long long m0 = __ballot(Lc.x == c);
            unsigned long long m1 = __ballot(Lc.y == c);
            unsigned long long m2 = __ballot(Lc.z == c);
            unsigned long long m3 = __ballot(Lc.w == c);
            const int c0 = __popcll(m0), c1 = __popcll(m1);
            const int c2 = __popcll(m2), c3 = __popcll(m3);
            if (Lc.x == c) wl[nl + __popcll(m0 & ltm)]           = sbase;
            if (Lc.y == c) wl[nl + c0 + __popcll(m1 & ltm)]      = sbase + 1;
            if (Lc.z == c) wl[nl + c0 + c1 + __popcll(m2 & ltm)] = sbase + 2;
            if (Lc.w == c) wl[nl + c0 + c1 + c2 + __popcll(m3 & ltm)] = sbase + 3;
            const int add = c0 + c1 + c2 + c3;
            nl += add; total += add;
            if (nl > LCAP - 256) drain();   // safety flush; never hit here
        }
    }
    drain();   // gather phase: 4-deep pipelined row loads

    // acc holds features 4*lane .. 4*lane+3 -> write partial row directly
    S_part4[(size_t)pair * 64 + lane] = acc;

    for (int off = 32; off; off >>= 1)
        acc2 += __shfl_down(acc2, off, 64);
    if (lane == 0) {
        cnt_part[pair] = (float)total;
        l2_part[pair]  = acc2;
    }
}

__global__ __launch_bounds__(1024) void ctc_finalize(
    const float* __restrict__ centers, const float* __restrict__ S_part,
    const float* __restrict__ cnt_part, const float* __restrict__ l2_part,
    float* __restrict__ class_loss, float* __restrict__ out_centers)
{
    const int c  = blockIdx.x;
    const int t  = threadIdx.x & 255;
    const int kq = threadIdx.x >> 8;     // 0..3, k-quarter

    float S = 0.f;
#pragma unroll
    for (int j = 0; j < 16; ++j)
        S += S_part[((size_t)c * K + kq * 16 + j) * FEAT + t];

    __shared__ float red[4][FEAT];
    __shared__ float r2[4];
    __shared__ float sn_s, sl2_s;
    red[kq][t] = S;

    if (threadIdx.x < 64) {
        float a = cnt_part[c * K + threadIdx.x];
        float b = l2_part[c * K + threadIdx.x];
        for (int off = 32; off; off >>= 1) {
            a += __shfl_down(a, off, 64);
            b += __shfl_down(b, off, 64);
        }
        if (threadIdx.x == 0) { sn_s = a; sl2_s = b; }
    }
    __syncthreads();

    if (threadIdx.x < 256) {
        const float Sf = red[0][t] + red[1][t] + red[2][t] + red[3][t];
        const float n  = sn_s;
        const float cc = centers[c * FEAT + t];
        out_centers[c * FEAT + t] = cc + ALPHA * (Sf - n * cc) / (1.f + n);
        float part = 0.5f * n * cc * cc - Sf * cc;
        for (int off = 32; off; off >>= 1) part += __shfl_down(part, off, 64);
        if ((t & 63) == 0) r2[t >> 6] = part;
    }
    __syncthreads();
    if (threadIdx.x == 0)
        class_loss[c] = r2[0] + r2[1] + r2[2] + r2[3] + 0.5f * sl2_s;
}

__global__ void ctc_loss_write(const float* __restrict__ class_loss,
                               float* __restrict__ out)
{
    const int l = threadIdx.x;   // 64 threads, one wave
    float v = (l < NCLS) ? class_loss[l] : 0.f;
    if (l + 64 < NCLS) v += class_loss[l + 64];
    for (int off = 32; off; off >>= 1) v += __shfl_down(v, off, 64);
    if (l == 0) out[0] = v;
}

extern "C" void kernel_launch(void* const* d_in, const int* in_sizes, int n_in,
                              void* d_out, int out_size, void* d_ws, size_t ws_size,
                              hipStream_t stream)
{
    const float* feat    = (const float*)d_in[0];
    const int*   labels  = (const int*)d_in[1];
    const float* centers = (const float*)d_in[2];
    float* out = (float*)d_out;
    float* ws  = (float*)d_ws;

    float* S_part     = ws + WS_S;
    float* cnt_part   = ws + WS_CNT;
    float* l2_part    = ws + WS_L2;
    float* class_loss = ws + WS_CLS;

    ctc_main<<<NCLS * K / 2, 128, 0, stream>>>(
        (const vf4*)feat, (const int4*)labels,
        (vf4*)S_part, cnt_part, l2_part);

    ctc_finalize<<<NCLS, 1024, 0, stream>>>(
        centers, S_part, cnt_part, l2_part, class_loss, out + 1);

    ctc_loss_write<<<1, 64, 0, stream>>>(class_loss, out);
}

// Round 8
// 32.683 us; speedup vs baseline: 1.2897x; 1.2897x over previous
//
#include <hip/hip_runtime.h>

#define ALPHA 0.5f
#define NCLS 86
#define FEAT 256
#define NTOT 131072

constexpr int K  = 64;          // sample chunks
constexpr int CH = NTOT / K;    // 2048 samples per chunk (one wave each)
constexpr int L4 = CH / 4;      // 512 int4 label-packs per chunk

// ws layout (floats):
//   S_part   [NCLS][K][FEAT]  = 1409024
//   cnt_part [NCLS][K]        = 5504
//   l2_part  [NCLS][K]        = 5504
//   class_loss [NCLS]         = 86
constexpr size_t WS_S   = 0;
constexpr size_t WS_CNT = (size_t)NCLS * K * FEAT;
constexpr size_t WS_L2  = WS_CNT + (size_t)NCLS * K;
constexpr size_t WS_CLS = WS_L2 + (size_t)NCLS * K;

// 128-thread blocks (2 waves): 2752 blocks = 10.75/CU, whole grid
// co-resident in one scheduling round (~21.5 waves/CU).
__global__ __launch_bounds__(128) void ctc_main(
    const float4* __restrict__ feat4, const int4* __restrict__ lab4,
    float4* __restrict__ S_part4, float* __restrict__ cnt_part,
    float* __restrict__ l2_part)
{
    const int wave = threadIdx.x >> 6;
    const int lane = threadIdx.x & 63;
    const int pair = blockIdx.x * 2 + wave;   // = c*K + k
    const int k = pair % K;
    const int c = pair / K;
    const int base = k * CH;                  // first sample of this chunk

    const int4* lp = lab4 + (base >> 2) + lane;
    // dummy row for empty-mask slots: chunk's own row 0 (L2-hot after 1st touch)
    const size_t dummy = (size_t)base * 64 + lane;

    float4 acc = {0.f, 0.f, 0.f, 0.f};
    float  acc2 = 0.f;
    int    cnt  = 0;   // wave-uniform (ballot popcounts)

    int4 L = lp[0];    // prefetched labels for current iteration
    for (int it = 0; it < L4; it += 64) {
        const int4 Lc = L;
        if (it + 64 < L4) L = lp[it + 64];    // prefetch next iter's labels
        unsigned long long m0 = __ballot(Lc.x == c);
        unsigned long long m1 = __ballot(Lc.y == c);
        unsigned long long m2 = __ballot(Lc.z == c);
        unsigned long long m3 = __ballot(Lc.w == c);
        cnt += __popcll(m0) + __popcll(m1) + __popcll(m2) + __popcll(m3);

        // cross-mask 4-wide drain: pop one bit from EACH mask per trip and
        // issue all 4 row-loads before any accumulate (~3 useful loads in
        // flight typical; empty slots re-read the L2-hot dummy row).
#define ACCUM(v)                                                           \
        { acc.x += v.x; acc.y += v.y; acc.z += v.z; acc.w += v.w;          \
          acc2  += v.x * v.x + v.y * v.y + v.z * v.z + v.w * v.w; }
        while (m0 | m1 | m2 | m3) {
            const bool h0 = m0 != 0, h1 = m1 != 0, h2 = m2 != 0, h3 = m3 != 0;
            const int b0 = (int)__ffsll((long long)m0) - 1;
            const int b1 = (int)__ffsll((long long)m1) - 1;
            const int b2 = (int)__ffsll((long long)m2) - 1;
            const int b3 = (int)__ffsll((long long)m3) - 1;
            m0 &= m0 - 1; m1 &= m1 - 1; m2 &= m2 - 1; m3 &= m3 - 1;
            const float4 v0 = feat4[h0 ? (size_t)(base + (it + b0) * 4 + 0) * 64 + lane : dummy];
            const float4 v1 = feat4[h1 ? (size_t)(base + (it + b1) * 4 + 1) * 64 + lane : dummy];
            const float4 v2 = feat4[h2 ? (size_t)(base + (it + b2) * 4 + 2) * 64 + lane : dummy];
            const float4 v3 = feat4[h3 ? (size_t)(base + (it + b3) * 4 + 3) * 64 + lane : dummy];
            if (h0) ACCUM(v0)
            if (h1) ACCUM(v1)
            if (h2) ACCUM(v2)
            if (h3) ACCUM(v3)
        }
#undef ACCUM
    }

    // acc holds features 4*lane .. 4*lane+3 -> write partial row directly
    S_part4[(size_t)pair * 64 + lane] = acc;

    for (int off = 32; off; off >>= 1)
        acc2 += __shfl_down(acc2, off, 64);
    if (lane == 0) {
        cnt_part[pair] = (float)cnt;
        l2_part[pair]  = acc2;
    }
}

__global__ __launch_bounds__(1024) void ctc_finalize(
    const float* __restrict__ centers, const float* __restrict__ S_part,
    const float* __restrict__ cnt_part, const float* __restrict__ l2_part,
    float* __restrict__ class_loss, float* __restrict__ out_centers)
{
    const int c  = blockIdx.x;
    const int t  = threadIdx.x & 255;
    const int kq = threadIdx.x >> 8;     // 0..3, k-quarter

    float S = 0.f;
#pragma unroll
    for (int j = 0; j < 16; ++j)
        S += S_part[((size_t)c * K + kq * 16 + j) * FEAT + t];

    __shared__ float red[4][FEAT];
    __shared__ float r2[4];
    __shared__ float sn_s, sl2_s;
    red[kq][t] = S;

    if (threadIdx.x < 64) {
        float a = cnt_part[c * K + threadIdx.x];
        float b = l2_part[c * K + threadIdx.x];
        for (int off = 32; off; off >>= 1) {
            a += __shfl_down(a, off, 64);
            b += __shfl_down(b, off, 64);
        }
        if (threadIdx.x == 0) { sn_s = a; sl2_s = b; }
    }
    __syncthreads();

    if (threadIdx.x < 256) {
        const float Sf = red[0][t] + red[1][t] + red[2][t] + red[3][t];
        const float n  = sn_s;
        const float cc = centers[c * FEAT + t];
        out_centers[c * FEAT + t] = cc + ALPHA * (Sf - n * cc) / (1.f + n);
        float part = 0.5f * n * cc * cc - Sf * cc;
        for (int off = 32; off; off >>= 1) part += __shfl_down(part, off, 64);
        if ((t & 63) == 0) r2[t >> 6] = part;
    }
    __syncthreads();
    if (threadIdx.x == 0)
        class_loss[c] = r2[0] + r2[1] + r2[2] + r2[3] + 0.5f * sl2_s;
}

__global__ void ctc_loss_write(const float* __restrict__ class_loss,
                               float* __restrict__ out)
{
    const int l = threadIdx.x;   // 64 threads, one wave
    float v = (l < NCLS) ? class_loss[l] : 0.f;
    if (l + 64 < NCLS) v += class_loss[l + 64];
    for (int off = 32; off; off >>= 1) v += __shfl_down(v, off, 64);
    if (l == 0) out[0] = v;
}

extern "C" void kernel_launch(void* const* d_in, const int* in_sizes, int n_in,
                              void* d_out, int out_size, void* d_ws, size_t ws_size,
                              hipStream_t stream)
{
    const float* feat    = (const float*)d_in[0];
    const int*   labels  = (const int*)d_in[1];
    const float* centers = (const float*)d_in[2];
    float* out = (float*)d_out;
    float* ws  = (float*)d_ws;

    float* S_part     = ws + WS_S;
    float* cnt_part   = ws + WS_CNT;
    float* l2_part    = ws + WS_L2;
    float* class_loss = ws + WS_CLS;

    ctc_main<<<NCLS * K / 2, 128, 0, stream>>>(
        (const float4*)feat, (const int4*)labels,
        (float4*)S_part, cnt_part, l2_part);

    ctc_finalize<<<NCLS, 1024, 0, stream>>>(
        centers, S_part, cnt_part, l2_part, class_loss, out + 1);

    ctc_loss_write<<<1, 64, 0, stream>>>(class_loss, out);
}